// Round 1
// baseline (3403.697 us; speedup 1.0000x reference)
//
#include <hip/hip_runtime.h>

#define DIM 512
#define NROWS 131072

typedef __attribute__((ext_vector_type(8))) __bf16 bf16x8;
typedef __attribute__((ext_vector_type(4))) float f32x4;

union BF8 { unsigned short us[8]; bf16x8 v; };

__device__ __forceinline__ unsigned short f2bf(float f) {
  unsigned u = __builtin_bit_cast(unsigned, f);
  return (unsigned short)((u + 0x7FFFu + ((u >> 16) & 1u)) >> 16);
}

__device__ __forceinline__ f32x4 mfma16(bf16x8 a, bf16x8 b, f32x4 c) {
  return __builtin_amdgcn_mfma_f32_16x16x32_bf16(a, b, c, 0, 0, 0);
}

__device__ __forceinline__ float sigmoid_fast(float v) {
  return 1.0f / (1.0f + __expf(-v));
}
__device__ __forceinline__ float tanh_fast(float v) {
  float e = __expf(2.0f * v);
  return 1.0f - 2.0f / (e + 1.0f);
}

// ---------------------------------------------------------------------------
// Weight pre-pack: fp32 [out=512][in=512] row-major  ->  bf16 B-fragments.
// Fragment (gate g, kstep f, colfrag c): lane l holds 8 contiguous bf16 =
// W[c*16 + (l&15)][f*32 + (l>>4)*8 + 0..7].  Element index:
//   ((g*16 + f)*32 + c)*64*8 + l*8 + e
// One thread per element. 6*2^18 = 1,572,864 threads.
// ---------------------------------------------------------------------------
__global__ void prepack_weights(const float* __restrict__ W0, const float* __restrict__ W1,
                                const float* __restrict__ W2, const float* __restrict__ W3,
                                const float* __restrict__ W4, const float* __restrict__ W5,
                                unsigned short* __restrict__ out) {
  int idx = blockIdx.x * 256 + threadIdx.x;
  int e = idx & 7;
  int l = (idx >> 3) & 63;
  int c = (idx >> 9) & 31;
  int f = (idx >> 14) & 15;
  int g = idx >> 18;
  const float* W = (g == 0) ? W0 : (g == 1) ? W1 : (g == 2) ? W2
                 : (g == 3) ? W3 : (g == 4) ? W4 : W5;
  int row = c * 16 + (l & 15);
  int kk  = f * 32 + ((l >> 4) << 3) + e;
  out[idx] = f2bf(W[row * DIM + kk]);
}

// K-loop over 16 k-steps: A from register array, B from packed global weights.
#define GEMM_REG(Aarr, g, cbase, acc)                                          \
  _Pragma("unroll")                                                            \
  for (int f = 0; f < 16; ++f) {                                               \
    const int base_ = (g) * 32768 + (f * 32 + (cbase)) * 64 + lane;            \
    acc[0] = mfma16(Aarr[f], wbv[base_      ], acc[0]);                        \
    acc[1] = mfma16(Aarr[f], wbv[base_ +  64], acc[1]);                        \
    acc[2] = mfma16(Aarr[f], wbv[base_ + 128], acc[2]);                        \
    acc[3] = mfma16(Aarr[f], wbv[base_ + 192], acc[3]);                        \
  }

// ---------------------------------------------------------------------------
// Fused GRU: one block = 64 rows. 8 waves: wave w -> rows 16*(w&3),
// column half (w>>2)*256. x,h kept in registers as bf16 A-fragments.
// rh staged in XOR-swizzled LDS for the chained (r*h)@W_nh.T GEMM.
// ---------------------------------------------------------------------------
__global__ __launch_bounds__(512, 2)
void gru_fused(const float* __restrict__ x, const float* __restrict__ h,
               const unsigned short* __restrict__ WB,
               const float* __restrict__ b_rx, const float* __restrict__ b_rh,
               const float* __restrict__ b_zx, const float* __restrict__ b_zh,
               const float* __restrict__ b_nx, const float* __restrict__ b_nh,
               float* __restrict__ out) {
  __shared__ short rhbuf[64 * 512];   // 64 KiB, element-index XOR swizzle <<3

  const int tid   = threadIdx.x;
  const int lane  = tid & 63;
  const int w     = tid >> 6;      // 0..7
  const int wr    = w & 3;         // row group (16 rows each)
  const int ch    = w >> 2;        // column half (0 or 1)
  const int row0  = blockIdx.x * 64;
  const int rloc0 = wr * 16;
  const int lrow  = lane & 15;
  const int kl    = (lane >> 4) * 8;

  const bf16x8* wbv = (const bf16x8*)WB;

  // ---- load x,h rows into register A-fragments (fp32 -> bf16) ----
  bf16x8 xa[16], ha[16];
  {
    const float* px = x + (size_t)(row0 + rloc0 + lrow) * DIM;
    const float* ph = h + (size_t)(row0 + rloc0 + lrow) * DIM;
#pragma unroll
    for (int f = 0; f < 16; ++f) {
      float4 a0 = *(const float4*)(px + f * 32 + kl);
      float4 a1 = *(const float4*)(px + f * 32 + kl + 4);
      float4 b0 = *(const float4*)(ph + f * 32 + kl);
      float4 b1 = *(const float4*)(ph + f * 32 + kl + 4);
      BF8 ux, uh;
      ux.us[0] = f2bf(a0.x); ux.us[1] = f2bf(a0.y); ux.us[2] = f2bf(a0.z); ux.us[3] = f2bf(a0.w);
      ux.us[4] = f2bf(a1.x); ux.us[5] = f2bf(a1.y); ux.us[6] = f2bf(a1.z); ux.us[7] = f2bf(a1.w);
      uh.us[0] = f2bf(b0.x); uh.us[1] = f2bf(b0.y); uh.us[2] = f2bf(b0.z); uh.us[3] = f2bf(b0.w);
      uh.us[4] = f2bf(b1.x); uh.us[5] = f2bf(b1.y); uh.us[6] = f2bf(b1.z); uh.us[7] = f2bf(b1.w);
      xa[f] = ux.v; ha[f] = uh.v;
    }
  }

  // ---- phase 1: r = sigmoid(x@Wrx.T + h@Wrh.T + b); rh = r*h -> LDS ----
#pragma unroll 1
  for (int t = 0; t < 4; ++t) {
    const int cb = ch * 16 + t * 4;           // col-frag base (16-col units)
    f32x4 acc[4] = {};
    GEMM_REG(xa, 0, cb, acc);                 // W_rx
    GEMM_REG(ha, 1, cb, acc);                 // W_rh
#pragma unroll
    for (int fi = 0; fi < 4; ++fi) {
      const int col = (cb + fi) * 16 + lrow;
      const float bsum = b_rx[col] + b_rh[col];
#pragma unroll
      for (int j = 0; j < 4; ++j) {
        const int rl = rloc0 + (lane >> 4) * 4 + j;        // local row 0..63
        float hv = h[(size_t)(row0 + rl) * DIM + col];     // L2-hot
        float rv = sigmoid_fast(acc[fi][j] + bsum);
        int idxE = (rl * DIM + col) ^ ((rl & 7) << 3);     // swizzled
        rhbuf[idxE] = (short)f2bf(rv * hv);
      }
    }
  }
  __syncthreads();

  // ---- phase 2: n = tanh(x@Wnx.T + rh@Wnh.T + b); z; out ----
#pragma unroll 1
  for (int t = 0; t < 4; ++t) {
    const int cb = ch * 16 + t * 4;
    f32x4 acc[4] = {};
    GEMM_REG(xa, 4, cb, acc);                 // W_nx
    {
      const int rl = rloc0 + lrow;
      const int sw = (rl & 7) << 3;
#pragma unroll
      for (int f = 0; f < 16; ++f) {
        int ridx = (rl * DIM + f * 32 + kl) ^ sw;
        bf16x8 a = *(const bf16x8*)&rhbuf[ridx];           // ds_read_b128
        const int base_ = 5 * 32768 + (f * 32 + cb) * 64 + lane;  // W_nh
        acc[0] = mfma16(a, wbv[base_      ], acc[0]);
        acc[1] = mfma16(a, wbv[base_ +  64], acc[1]);
        acc[2] = mfma16(a, wbv[base_ + 128], acc[2]);
        acc[3] = mfma16(a, wbv[base_ + 192], acc[3]);
      }
    }
    f32x4 nv[4];
#pragma unroll
    for (int fi = 0; fi < 4; ++fi) {
      const int col = (cb + fi) * 16 + lrow;
      const float bsum = b_nx[col] + b_nh[col];
#pragma unroll
      for (int j = 0; j < 4; ++j)
        nv[fi][j] = tanh_fast(acc[fi][j] + bsum);
    }
    // z-gate
    f32x4 accz[4] = {};
    GEMM_REG(xa, 2, cb, accz);                // W_zx
    GEMM_REG(ha, 3, cb, accz);                // W_zh
#pragma unroll
    for (int fi = 0; fi < 4; ++fi) {
      const int col = (cb + fi) * 16 + lrow;
      const float bsum = b_zx[col] + b_zh[col];
#pragma unroll
      for (int j = 0; j < 4; ++j) {
        const int rl = rloc0 + (lane >> 4) * 4 + j;
        float hv = h[(size_t)(row0 + rl) * DIM + col];
        float zv = sigmoid_fast(accz[fi][j] + bsum);
        out[(size_t)(row0 + rl) * DIM + col] = (1.0f - zv) * nv[fi][j] + zv * hv;
      }
    }
  }
}

extern "C" void kernel_launch(void* const* d_in, const int* in_sizes, int n_in,
                              void* d_out, int out_size, void* d_ws, size_t ws_size,
                              hipStream_t stream) {
  const float* x    = (const float*)d_in[0];
  const float* h    = (const float*)d_in[1];
  const float* W_rx = (const float*)d_in[2];
  const float* b_rx = (const float*)d_in[3];
  const float* W_rh = (const float*)d_in[4];
  const float* b_rh = (const float*)d_in[5];
  const float* W_zx = (const float*)d_in[6];
  const float* b_zx = (const float*)d_in[7];
  const float* W_zh = (const float*)d_in[8];
  const float* b_zh = (const float*)d_in[9];
  const float* W_nx = (const float*)d_in[10];
  const float* b_nx = (const float*)d_in[11];
  const float* W_nh = (const float*)d_in[12];
  const float* b_nh = (const float*)d_in[13];

  unsigned short* wpack = (unsigned short*)d_ws;   // 3 MiB needed

  // gates: 0=W_rx 1=W_rh 2=W_zx 3=W_zh 4=W_nx 5=W_nh
  prepack_weights<<<6144, 256, 0, stream>>>(W_rx, W_rh, W_zx, W_zh, W_nx, W_nh, wpack);
  gru_fused<<<NROWS / 64, 512, 0, stream>>>(x, h, wpack,
                                            b_rx, b_rh, b_zx, b_zh, b_nx, b_nh,
                                            (float*)d_out);
}

// Round 2
// 1301.392 us; speedup vs baseline: 2.6154x; 2.6154x over previous
//
#include <hip/hip_runtime.h>

#define DIM 512
#define NROWS 131072

typedef __attribute__((ext_vector_type(8))) __bf16 bf16x8;
typedef __attribute__((ext_vector_type(4))) float f32x4;

union BF8 { unsigned short us[8]; bf16x8 v; };

__device__ __forceinline__ unsigned short f2bf(float f) {
  unsigned u = __builtin_bit_cast(unsigned, f);
  return (unsigned short)((u + 0x7FFFu + ((u >> 16) & 1u)) >> 16);
}

__device__ __forceinline__ f32x4 mfma16(bf16x8 a, bf16x8 b, f32x4 c) {
  return __builtin_amdgcn_mfma_f32_16x16x32_bf16(a, b, c, 0, 0, 0);
}

__device__ __forceinline__ float sigmoid_fast(float v) {
  return 1.0f / (1.0f + __expf(-v));
}
__device__ __forceinline__ float tanh_fast(float v) {
  float e = __expf(2.0f * v);
  return 1.0f - 2.0f / (e + 1.0f);
}

__device__ __forceinline__ void gl2lds(const unsigned char* g, unsigned char* l) {
  __builtin_amdgcn_global_load_lds(
      (const __attribute__((address_space(1))) unsigned int*)g,
      (__attribute__((address_space(3))) unsigned int*)l, 16, 0, 0);
}

// ---------------------------------------------------------------------------
// Weight pre-pack: fp32 W[out=512][in=512] -> bf16 B-fragments.
// Frag (gate g, kstep f, colfrag c): lane l holds 8 bf16 =
//   W[c*16 + (l&15)][f*32 + (l>>4)*8 + 0..7]
// elem index = ((g*16+f)*32 + c)*512 + l*8 + e.  Gate order: rx,zx,nx,rh,zh,nh.
// ---------------------------------------------------------------------------
__global__ void prepack_weights(const float* __restrict__ W0, const float* __restrict__ W1,
                                const float* __restrict__ W2, const float* __restrict__ W3,
                                const float* __restrict__ W4, const float* __restrict__ W5,
                                unsigned short* __restrict__ out) {
  int idx = blockIdx.x * 256 + threadIdx.x;
  int e = idx & 7;
  int l = (idx >> 3) & 63;
  int c = (idx >> 9) & 31;
  int f = (idx >> 14) & 15;
  int g = idx >> 18;
  const float* W = (g == 0) ? W0 : (g == 1) ? W1 : (g == 2) ? W2
                 : (g == 3) ? W3 : (g == 4) ? W4 : W5;
  int row = c * 16 + (l & 15);
  int kk  = f * 32 + ((l >> 4) << 3) + e;
  out[idx] = f2bf(W[row * DIM + kk]);
}

#define LDS_BYTES 147456           // 2x64K B dbuf + 16K xh slice
#define XH_OFF    131072

// one gate-GEMM k-slice (BK=64, 2 k-steps): A from xh LDS, B from buf bB
#define GATE_COMPUTE(ACC, MOFF, bB)                                            \
  _Pragma("unroll")                                                            \
  for (int ks = 0; ks < 2; ++ks) {                                             \
    bf16x8 af[4], bfr[4];                                                      \
    _Pragma("unroll")                                                          \
    for (int rf = 0; rf < 4; ++rf)                                             \
      af[rf] = *(const bf16x8*)&lds[XH_OFF + (MOFF) + (ks*4+rf)*1024 + lane*16]; \
    _Pragma("unroll")                                                          \
    for (int cf = 0; cf < 4; ++cf)                                             \
      bfr[cf] = *(const bf16x8*)&lds[(bB) + (ks*32 + cfg0 + cf)*1024 + lane*16]; \
    _Pragma("unroll")                                                          \
    for (int rf = 0; rf < 4; ++rf)                                             \
      _Pragma("unroll")                                                        \
      for (int cf = 0; cf < 4; ++cf)                                           \
        ACC[rf][cf] = mfma16(af[rf], bfr[cf], ACC[rf][cf]);                    \
  }

// ---------------------------------------------------------------------------
// Fused GRU. Block = 64 rows x 512 cols, 512 thr (8 waves), wave = 64r x 64c.
// Main K-sweep: 5 gate-stages per 64-k slice {rx,zx,nx,rh,zh}, B dbuf'd via
// global_load_lds, accR/accZ/accN accumulate across all slices.
// Phase 2: rh -> frag-packed LDS (aliases buf0), nh GEMM BK=32 dbuf in buf1.
// ---------------------------------------------------------------------------
__global__ __launch_bounds__(512, 2)
void gru_fused(const float* __restrict__ x, const float* __restrict__ h,
               const unsigned char* __restrict__ WB,
               const float* __restrict__ b_rx, const float* __restrict__ b_rh,
               const float* __restrict__ b_zx, const float* __restrict__ b_zh,
               const float* __restrict__ b_nx, const float* __restrict__ b_nh,
               float* __restrict__ out) {
  __shared__ __align__(1024) unsigned char lds[LDS_BYTES];

  const int tid  = threadIdx.x;
  const int lane = tid & 63;
  const int w    = tid >> 6;        // 0..7: col group (64 cols)
  const int cfg0 = w * 4;           // first 16-col fragment of this wave
  const int row0 = blockIdx.x * 64;
  const int lr   = lane & 15;
  const int lk   = lane >> 4;       // 0..3

  f32x4 accR[4][4] = {}, accZ[4][4] = {}, accN[4][4] = {};

  // ---- staging helpers ----
  auto stageB = [&](int g, int s, int buf) {     // 64KB: gate g, slice s
    const unsigned char* src = WB + (size_t)(g * 16 + s * 2) * 32768;
#pragma unroll
    for (int it = 0; it < 8; ++it) {
      int o = (it * 512 + tid) * 16;
      gl2lds(src + o, &lds[(buf << 16) + o]);
    }
  };
  auto stageNH = [&](int s2, int pb) {           // 32KB: Wnh k-step s2
    const unsigned char* src = WB + (size_t)(80 + s2) * 32768;
#pragma unroll
    for (int it = 0; it < 4; ++it) {
      int o = (it * 512 + tid) * 16;
      gl2lds(src + o, &lds[65536 + pb * 32768 + o]);
    }
  };

  // xh slice prefetch regs: wave w stages frag (rf=w&3, ks=w>>2) of x and h
  float4 xr0, xr1, hr0, hr1;
  auto issueXH = [&](int s) {
    const size_t roff = (size_t)(row0 + (w & 3) * 16 + lr) * DIM
                        + s * 64 + (w >> 2) * 32 + lk * 8;
    xr0 = *(const float4*)(x + roff); xr1 = *(const float4*)(x + roff + 4);
    hr0 = *(const float4*)(h + roff); hr1 = *(const float4*)(h + roff + 4);
  };
  auto writeXH = [&]() {
    BF8 ux, uh;
    ux.us[0]=f2bf(xr0.x); ux.us[1]=f2bf(xr0.y); ux.us[2]=f2bf(xr0.z); ux.us[3]=f2bf(xr0.w);
    ux.us[4]=f2bf(xr1.x); ux.us[5]=f2bf(xr1.y); ux.us[6]=f2bf(xr1.z); ux.us[7]=f2bf(xr1.w);
    uh.us[0]=f2bf(hr0.x); uh.us[1]=f2bf(hr0.y); uh.us[2]=f2bf(hr0.z); uh.us[3]=f2bf(hr0.w);
    uh.us[4]=f2bf(hr1.x); uh.us[5]=f2bf(hr1.y); uh.us[6]=f2bf(hr1.z); uh.us[7]=f2bf(hr1.w);
    *(bf16x8*)&lds[XH_OFF        + w * 1024 + lane * 16] = ux.v;
    *(bf16x8*)&lds[XH_OFF + 8192 + w * 1024 + lane * 16] = uh.v;
  };

  // ---- prologue: stage B(rx, slice0) + xh(0) ----
  stageB(0, 0, 0);
  issueXH(0);
  writeXH();
  __syncthreads();

  // ---- main K-sweep: 8 slices x 5 gate-stages ----
  int bb = 0;                        // buffer holding current stage
#pragma unroll 1
  for (int s = 0; s < 8; ++s) {
    // g=0: rx
    stageB(1, s, bb ^ 1);
    GATE_COMPUTE(accR, 0, bb << 16);
    __syncthreads(); bb ^= 1;
    // g=1: zx
    stageB(2, s, bb ^ 1);
    GATE_COMPUTE(accZ, 0, bb << 16);
    __syncthreads(); bb ^= 1;
    // g=2: nx
    stageB(3, s, bb ^ 1);
    GATE_COMPUTE(accN, 0, bb << 16);
    __syncthreads(); bb ^= 1;
    // g=3: rh
    stageB(4, s, bb ^ 1);
    GATE_COMPUTE(accR, 8192, bb << 16);
    __syncthreads(); bb ^= 1;
    // g=4: zh (+ prefetch next slice's rx and xh)
    if (s < 7) { stageB(0, s + 1, bb ^ 1); issueXH(s + 1); }
    GATE_COMPUTE(accZ, 8192, bb << 16);
    __syncthreads(); bb ^= 1;
    if (s < 7) { writeXH(); __syncthreads(); }
  }

  // ---- phase 2 prologue: issue Wnh k-step 0 while computing rh ----
  stageNH(0, 0);

  // r epilogue: r = sigmoid(accR + b), rh = r*h -> frag-packed LDS (offset 0)
#pragma unroll
  for (int cf = 0; cf < 4; ++cf) {
    const int col = (cfg0 + cf) * 16 + lr;
    const float bs = b_rx[col] + b_rh[col];
    const int fr    = (col >> 5) * 4;          // frag row-base for this col
    const int lane2 = ((col >> 3) & 3) * 16;   // k-subchunk slot
    const int eoff  = (col & 7) * 2;
#pragma unroll
    for (int rf = 0; rf < 4; ++rf) {
#pragma unroll
      for (int j = 0; j < 4; ++j) {
        const int rowl = rf * 16 + lk * 4 + j;
        float hv = h[(size_t)(row0 + rowl) * DIM + col];
        float rv = sigmoid_fast(accR[rf][cf][j] + bs);
        *(unsigned short*)&lds[(fr + rf) * 1024 + (lane2 + (rowl & 15)) * 16 + eoff]
            = f2bf(rv * hv);
      }
    }
  }
  __syncthreads();

  // ---- phase 2: accN += rh @ Wnh.T, BK=32, dbuf in buf1 region ----
  int pb = 0;
#pragma unroll 1
  for (int s2 = 0; s2 < 16; ++s2) {
    if (s2 < 15) stageNH(s2 + 1, pb ^ 1);
    bf16x8 af[4], bfr[4];
#pragma unroll
    for (int rf = 0; rf < 4; ++rf)
      af[rf] = *(const bf16x8*)&lds[(s2 * 4 + rf) * 1024 + lane * 16];
#pragma unroll
    for (int cf = 0; cf < 4; ++cf)
      bfr[cf] = *(const bf16x8*)&lds[65536 + pb * 32768 + (cfg0 + cf) * 1024 + lane * 16];
#pragma unroll
    for (int rf = 0; rf < 4; ++rf)
#pragma unroll
      for (int cf = 0; cf < 4; ++cf)
        accN[rf][cf] = mfma16(af[rf], bfr[cf], accN[rf][cf]);
    __syncthreads(); pb ^= 1;
  }

  // ---- final epilogue: n = tanh(accN+b), z = sigmoid(accZ+b), combine ----
#pragma unroll
  for (int cf = 0; cf < 4; ++cf) {
    const int col = (cfg0 + cf) * 16 + lr;
    const float bn = b_nx[col] + b_nh[col];
    const float bz = b_zx[col] + b_zh[col];
#pragma unroll
    for (int rf = 0; rf < 4; ++rf) {
#pragma unroll
      for (int j = 0; j < 4; ++j) {
        const int rowl = rf * 16 + lk * 4 + j;
        const size_t off = (size_t)(row0 + rowl) * DIM + col;
        float hv = h[off];
        float nv = tanh_fast(accN[rf][cf][j] + bn);
        float zv = sigmoid_fast(accZ[rf][cf][j] + bz);
        out[off] = (1.0f - zv) * nv + zv * hv;
      }
    }
  }
}

extern "C" void kernel_launch(void* const* d_in, const int* in_sizes, int n_in,
                              void* d_out, int out_size, void* d_ws, size_t ws_size,
                              hipStream_t stream) {
  const float* x    = (const float*)d_in[0];
  const float* h    = (const float*)d_in[1];
  const float* W_rx = (const float*)d_in[2];
  const float* b_rx = (const float*)d_in[3];
  const float* W_rh = (const float*)d_in[4];
  const float* b_rh = (const float*)d_in[5];
  const float* W_zx = (const float*)d_in[6];
  const float* b_zx = (const float*)d_in[7];
  const float* W_zh = (const float*)d_in[8];
  const float* b_zh = (const float*)d_in[9];
  const float* W_nx = (const float*)d_in[10];
  const float* b_nx = (const float*)d_in[11];
  const float* W_nh = (const float*)d_in[12];
  const float* b_nh = (const float*)d_in[13];

  unsigned short* wpack = (unsigned short*)d_ws;   // 3 MiB

  // gate order: rx, zx, nx, rh, zh, nh
  prepack_weights<<<6144, 256, 0, stream>>>(W_rx, W_zx, W_nx, W_rh, W_zh, W_nh, wpack);
  gru_fused<<<NROWS / 64, 512, 0, stream>>>(x, h, (const unsigned char*)wpack,
                                            b_rx, b_rh, b_zx, b_zh, b_nx, b_nh,
                                            (float*)d_out);
}

// Round 3
// 766.247 us; speedup vs baseline: 4.4420x; 1.6984x over previous
//
#include <hip/hip_runtime.h>

#define DIM 512
#define NROWS 131072

typedef __attribute__((ext_vector_type(8))) __bf16 bf16x8;
typedef __attribute__((ext_vector_type(4))) float f32x4;

__device__ __forceinline__ unsigned short f2bf(float f) {
  unsigned u = __builtin_bit_cast(unsigned, f);
  return (unsigned short)((u + 0x7FFFu + ((u >> 16) & 1u)) >> 16);
}
__device__ __forceinline__ float bf2f(unsigned short u) {
  return __builtin_bit_cast(float, (unsigned)u << 16);
}

__device__ __forceinline__ f32x4 mfma16(bf16x8 a, bf16x8 b, f32x4 c) {
  return __builtin_amdgcn_mfma_f32_16x16x32_bf16(a, b, c, 0, 0, 0);
}

__device__ __forceinline__ float sigmoid_fast(float v) {
  return 1.0f / (1.0f + __expf(-v));
}
__device__ __forceinline__ float tanh_fast(float v) {
  float e = __expf(2.0f * v);
  return 1.0f - 2.0f / (e + 1.0f);
}

__device__ __forceinline__ void gl2lds(const unsigned char* g, unsigned char* l) {
  __builtin_amdgcn_global_load_lds(
      (const __attribute__((address_space(1))) unsigned int*)g,
      (__attribute__((address_space(3))) unsigned int*)l, 16, 0, 0);
}

// ---------------------------------------------------------------------------
// Weight pre-pack: fp32 W[out=512][in=512] -> bf16 B-fragments.
// Frag (gate g, kstep f, colfrag c): lane l holds 8 bf16 =
//   W[c*16 + (l&15)][f*32 + (l>>4)*8 + 0..7]
// elem index = ((g*16+f)*32 + c)*512 + l*8 + e.  Gate order: rx,zx,rh,zh,nx,nh.
// ---------------------------------------------------------------------------
__global__ void prepack_weights(const float* __restrict__ W0, const float* __restrict__ W1,
                                const float* __restrict__ W2, const float* __restrict__ W3,
                                const float* __restrict__ W4, const float* __restrict__ W5,
                                unsigned short* __restrict__ out) {
  int idx = blockIdx.x * 256 + threadIdx.x;
  int e = idx & 7;
  int l = (idx >> 3) & 63;
  int c = (idx >> 9) & 31;
  int f = (idx >> 14) & 15;
  int g = idx >> 18;
  const float* W = (g == 0) ? W0 : (g == 1) ? W1 : (g == 2) ? W2
                 : (g == 3) ? W3 : (g == 4) ? W4 : W5;
  int row = c * 16 + (l & 15);
  int kk  = f * 32 + ((l >> 4) << 3) + e;
  out[idx] = f2bf(W[row * DIM + kk]);
}

// LDS map (bytes):
//   [0, 64K)      sweep1: h frags [f16][rf4][lane64][16B]; sweep2: B dbuf 2x32K
//   [64K, 128K)   sweep1: B dbuf 2x32K; after r-epilogue: rh frags [f][rf][lane][16B]
//   [128K, 136K)  x slice dbuf 2x4K  [rf4][lane64][16B]
#define RH_OFF 65536
#define X_OFF  131072
#define LDS_BYTES 139264

// ---------------------------------------------------------------------------
// Fused GRU. Block = 64 rows x 512 cols, 512 thr (8 waves), wave = 64r x 64c.
// Sweep1: accR+accZ over {rx,zx,rh,zh}; rh -> frag-packed LDS.
// Sweep2: accN over {nx, nh(A=rh from LDS)}; combine epilogue.
// ---------------------------------------------------------------------------
__global__ __launch_bounds__(512, 1)
void gru_fused(const float* __restrict__ x, const float* __restrict__ h,
               const unsigned char* __restrict__ WB,
               const float* __restrict__ b_rx, const float* __restrict__ b_rh,
               const float* __restrict__ b_zx, const float* __restrict__ b_zh,
               const float* __restrict__ b_nx, const float* __restrict__ b_nh,
               float* __restrict__ out) {
  __shared__ __align__(1024) unsigned char lds[LDS_BYTES];

  const int tid  = threadIdx.x;
  const int lane = tid & 63;
  const int w    = tid >> 6;        // 0..7: col group (64 cols)
  const int cfg0 = w * 4;           // first 16-col fragment of this wave
  const int row0 = blockIdx.x * 64;
  const int lr   = lane & 15;
  const int lk   = lane >> 4;       // 0..3

  // ---- helpers ----
  auto stageChunk = [&](int g, int f, int dstOff) {   // 32KB = one k-step
    const unsigned char* src = WB + (size_t)(g * 16 + f) * 32768;
#pragma unroll
    for (int it = 0; it < 4; ++it) {
      int o = (it * 512 + tid) * 16;
      gl2lds(src + o, &lds[dstOff + o]);
    }
  };

  float4 xreg;
  auto loadX = [&](int f) {
    int row = tid >> 3, kq = tid & 7;
    xreg = *(const float4*)(x + (size_t)(row0 + row) * DIM + f * 32 + kq * 4);
  };
  auto writeX = [&](int f) {
    int row = tid >> 3, kq = tid & 7;
    union { unsigned short us[4]; uint2 v; } p;
    p.us[0] = f2bf(xreg.x); p.us[1] = f2bf(xreg.y);
    p.us[2] = f2bf(xreg.z); p.us[3] = f2bf(xreg.w);
    *(uint2*)&lds[X_OFF + (f & 1) * 4096 + (row >> 4) * 1024
                  + ((kq >> 1) * 16 + (row & 15)) * 16 + (kq & 1) * 8] = p.v;
  };

  auto gateStage = [&](int abase, int bbase, f32x4 (&A)[4][4]) {
    bf16x8 af[4], bfr[4];
#pragma unroll
    for (int rf = 0; rf < 4; ++rf)
      af[rf] = *(const bf16x8*)&lds[abase + rf * 1024 + lane * 16];
#pragma unroll
    for (int cf = 0; cf < 4; ++cf)
      bfr[cf] = *(const bf16x8*)&lds[bbase + (cfg0 + cf) * 1024 + lane * 16];
#pragma unroll
    for (int rf = 0; rf < 4; ++rf)
#pragma unroll
      for (int cf = 0; cf < 4; ++cf)
        A[rf][cf] = mfma16(af[rf], bfr[cf], A[rf][cf]);
  };

  f32x4 accR[4][4] = {}, accZ[4][4] = {};

  // ---- prologue: stage full h (64 rows x 512 k) into frag LDS + x slice 0 ----
#pragma unroll
  for (int it = 0; it < 16; ++it) {
    int i = tid + it * 512;          // 0..8191
    int row = i >> 7, kf4 = i & 127;
    int k = kf4 * 4;
    float4 hv4 = *(const float4*)(h + (size_t)(row0 + row) * DIM + k);
    union { unsigned short us[4]; uint2 v; } p;
    p.us[0] = f2bf(hv4.x); p.us[1] = f2bf(hv4.y);
    p.us[2] = f2bf(hv4.z); p.us[3] = f2bf(hv4.w);
    *(uint2*)&lds[(k >> 5) * 4096 + (row >> 4) * 1024
                  + (((k >> 3) & 3) * 16 + (row & 15)) * 16 + (k & 4) * 2] = p.v;
  }
  loadX(0); writeX(0);
  stageChunk(0, 0, RH_OFF);          // rx_0 -> buf0
  __syncthreads();

  // ---- sweep 1: 16 k-steps x {rx, zx, rh, zh} ----
#pragma unroll 1
  for (int f = 0; f < 16; ++f) {
    const int xoff = X_OFF + (f & 1) * 4096;
    const int hoff = f * 4096;
    // g0: rx (A=x, accR), B in buf0; stage zx_f -> buf1
    stageChunk(1, f, RH_OFF + 32768);
    if (f < 15) loadX(f + 1);
    gateStage(xoff, RH_OFF, accR);
    __syncthreads();
    // g1: zx (A=x, accZ), B in buf1; stage rh_f -> buf0
    stageChunk(2, f, RH_OFF);
    gateStage(xoff, RH_OFF + 32768, accZ);
    __syncthreads();
    // g2: rh (A=h, accR), B in buf0; stage zh_f -> buf1
    stageChunk(3, f, RH_OFF + 32768);
    if (f < 15) writeX(f + 1);
    gateStage(hoff, RH_OFF, accR);
    __syncthreads();
    // g3: zh (A=h, accZ), B in buf1; stage rx_{f+1} -> buf0
    if (f < 15) stageChunk(0, f + 1, RH_OFF);
    gateStage(hoff, RH_OFF + 32768, accZ);
    __syncthreads();
  }

  // ---- r-epilogue: r = sigmoid(accR+b); rh = r*h -> frag-packed LDS @RH_OFF ----
#pragma unroll
  for (int cf = 0; cf < 4; ++cf) {
    const int col  = (cfg0 + cf) * 16 + lr;
    const float bs = b_rx[col] + b_rh[col];
    const int fcol  = col >> 5;
    const int l2b   = ((col >> 3) & 3) * 16;
    const int ebyte = (col & 7) * 2;
#pragma unroll
    for (int rf = 0; rf < 4; ++rf) {
#pragma unroll
      for (int j = 0; j < 4; ++j) {
        const int rsub = lk * 4 + j;                 // 0..15, row = rf*16+rsub
        unsigned short hu = *(const unsigned short*)
            &lds[fcol * 4096 + rf * 1024 + (l2b + rsub) * 16 + ebyte];
        float rv = sigmoid_fast(accR[rf][cf][j] + bs);
        *(unsigned short*)
            &lds[RH_OFF + fcol * 4096 + rf * 1024 + (l2b + rsub) * 16 + ebyte]
            = f2bf(rv * bf2f(hu));
      }
    }
  }
  __syncthreads();

  // ---- sweep 2: accN over {nx (A=x), nh (A=rh frags)}; B dbuf now @0 ----
  f32x4 accN[4][4] = {};
  loadX(0); writeX(0);
  stageChunk(4, 0, 0);               // nx_0 -> buf0 (h region dead)
  __syncthreads();
#pragma unroll 1
  for (int f = 0; f < 16; ++f) {
    const int xoff = X_OFF + (f & 1) * 4096;
    // nx: B in buf0; stage nh_f -> buf1
    stageChunk(5, f, 32768);
    if (f < 15) loadX(f + 1);
    gateStage(xoff, 0, accN);
    __syncthreads();
    // nh: A = rh frags (resident in LDS), B in buf1; stage nx_{f+1} -> buf0
    if (f < 15) { stageChunk(4, f + 1, 0); writeX(f + 1); }
    gateStage(RH_OFF + f * 4096, 32768, accN);
    __syncthreads();
  }

  // ---- final epilogue: n = tanh(accN+b), z = sigmoid(accZ+b), combine ----
#pragma unroll
  for (int cf = 0; cf < 4; ++cf) {
    const int col  = (cfg0 + cf) * 16 + lr;
    const float bn = b_nx[col] + b_nh[col];
    const float bz = b_zx[col] + b_zh[col];
#pragma unroll
    for (int rf = 0; rf < 4; ++rf) {
#pragma unroll
      for (int j = 0; j < 4; ++j) {
        const int row = rf * 16 + lk * 4 + j;
        const size_t off = (size_t)(row0 + row) * DIM + col;
        float hv = h[off];
        float nv = tanh_fast(accN[rf][cf][j] + bn);
        float zv = sigmoid_fast(accZ[rf][cf][j] + bz);
        out[off] = (1.0f - zv) * nv + zv * hv;
      }
    }
  }
}

extern "C" void kernel_launch(void* const* d_in, const int* in_sizes, int n_in,
                              void* d_out, int out_size, void* d_ws, size_t ws_size,
                              hipStream_t stream) {
  const float* x    = (const float*)d_in[0];
  const float* h    = (const float*)d_in[1];
  const float* W_rx = (const float*)d_in[2];
  const float* b_rx = (const float*)d_in[3];
  const float* W_rh = (const float*)d_in[4];
  const float* b_rh = (const float*)d_in[5];
  const float* W_zx = (const float*)d_in[6];
  const float* b_zx = (const float*)d_in[7];
  const float* W_zh = (const float*)d_in[8];
  const float* b_zh = (const float*)d_in[9];
  const float* W_nx = (const float*)d_in[10];
  const float* b_nx = (const float*)d_in[11];
  const float* W_nh = (const float*)d_in[12];
  const float* b_nh = (const float*)d_in[13];

  unsigned short* wpack = (unsigned short*)d_ws;   // 3 MiB

  // gate order: rx, zx, rh, zh, nx, nh
  prepack_weights<<<6144, 256, 0, stream>>>(W_rx, W_zx, W_rh, W_zh, W_nx, W_nh, wpack);
  gru_fused<<<NROWS / 64, 512, 0, stream>>>(x, h, (const unsigned char*)wpack,
                                            b_rx, b_rh, b_zx, b_zh, b_nx, b_nh,
                                            (float*)d_out);
}